// Round 1
// baseline (31035.443 us; speedup 1.0000x reference)
//
#include <hip/hip_runtime.h>
#include <hip/hip_bf16.h>

// ---------------------------------------------------------------------------
// LSTM model: embed -> 4x LSTM(256) -> FC(128). B=128, T=1024, E=H=256.
// Round 0: bf16-MFMA everywhere (fp32 accum + fp32 gate math / cell state).
// Per-layer persistent scan kernel, 64 wgs, custom device-scope grid barrier.
// ---------------------------------------------------------------------------

#define B_ 128
#define T_ 1024
#define H_ 256
#define NWG 64

typedef __attribute__((ext_vector_type(8))) short bf16x8;
typedef __attribute__((ext_vector_type(4))) float f32x4;

__device__ inline unsigned short f2bf(float f) {
  union { float f; unsigned u; } a; a.f = f;
  unsigned r = a.u + 0x7FFFu + ((a.u >> 16) & 1u);   // RNE
  return (unsigned short)(r >> 16);
}

__device__ inline bf16x8 pack8(float4 a, float4 b) {
  bf16x8 v;
  v[0] = (short)f2bf(a.x); v[1] = (short)f2bf(a.y);
  v[2] = (short)f2bf(a.z); v[3] = (short)f2bf(a.w);
  v[4] = (short)f2bf(b.x); v[5] = (short)f2bf(b.y);
  v[6] = (short)f2bf(b.z); v[7] = (short)f2bf(b.w);
  return v;
}

__device__ inline float sigmoidf_(float x) { return 1.0f / (1.0f + __expf(-x)); }
__device__ inline float tanhf_(float x) {
  float ax = fabsf(x);
  float e = __expf(-2.0f * ax);
  float t = (1.0f - e) / (1.0f + e);
  return copysignf(t, x);
}

// ---------------------------------------------------------------------------
__global__ void init_kernel(unsigned* bar) {
  if (threadIdx.x < 16) bar[threadIdx.x] = 0u;
}

// embed: xb0[t][b][e] = bf16(table[x[b][t]][e])
__global__ __launch_bounds__(256) void embed_kernel(
    const int* __restrict__ x, const float* __restrict__ table,
    unsigned short* __restrict__ xb0) {
  const int gid = blockIdx.x * 256 + threadIdx.x;    // T*B*32 chunks of 8 bf16
  const int row = gid >> 5;                          // t*B + b
  const int ch  = gid & 31;
  const int b = row & (B_ - 1), t = row >> 7;
  const int idx = x[b * T_ + t];
  const float* src = table + idx * 256 + ch * 8;
  float4 f0 = *(const float4*)src;
  float4 f1 = *(const float4*)(src + 4);
  bf16x8 v = pack8(f0, f1);
  *(bf16x8*)(xb0 + (size_t)row * 256 + ch * 8) = v;
}

// ---------------------------------------------------------------------------
// Persistent per-layer LSTM scan.
// Grid 64 = 4 b-tiles(32) x 16 k-tiles(16 cells -> 64 gate rows, k-major j=k*4+gate).
// Waves: 2 b-subs(16) x 2 j-subs(32 gate rows). Weights (B-frags) in registers.
__global__ __launch_bounds__(256, 1) void lstm_scan(
    const unsigned short* __restrict__ xin, unsigned short* __restrict__ xout,
    const float* __restrict__ Wih, const float* __restrict__ Whh,
    const float* __restrict__ bih, const float* __restrict__ bhh,
    const float* __restrict__ h0, const float* __restrict__ c0,
    float* __restrict__ hN, float* __restrict__ cN,
    unsigned* bar) {
  __shared__ uint4 AbufV[2048];          // [32 rows][512 bf16] = 32KB, XOR-swizzled 16B chunks
  __shared__ float Gbuf[32 * 64];        // gate preacts [b_local][j_lds]
  __shared__ float Cbuf[512];            // cell state [b_local*16 + k_local]
  __shared__ float BIAS[64];
  char* Abuf = (char*)AbufV;

  const int tid  = threadIdx.x;
  const int wv   = tid >> 6, lane = tid & 63, lhi = lane >> 4, llo = lane & 15;
  const int bt   = blockIdx.x & 3, kt = blockIdx.x >> 2;
  const int b0   = bt * 32, k0 = kt * 16;
  const int jsub = wv & 1, bsub = wv >> 1;

  // ---- load weight B-fragments straight from global fp32 into registers ----
  bf16x8 bw[2][16];
#pragma unroll
  for (int jf = 0; jf < 2; ++jf) {
    const int jlds  = jsub * 32 + jf * 16 + llo;     // 0..63, k-major
    const int kcell = jlds >> 2, gate = jlds & 3;
    const int jg    = gate * 256 + k0 + kcell;       // global gate row (i,f,g,o blocks)
#pragma unroll
    for (int ks = 0; ks < 16; ++ks) {
      const int q = ks * 4 + lhi;                    // logical 16B chunk (8 k-elems)
      const float* src = (q < 32) ? (Wih + jg * 256 + q * 8)
                                  : (Whh + jg * 256 + (q - 32) * 8);
      float4 f0 = *(const float4*)src;
      float4 f1 = *(const float4*)(src + 4);
      bw[jf][ks] = pack8(f0, f1);
    }
  }

  if (tid < 64) {
    const int kcell = tid >> 2, gate = tid & 3;
    const int jg = gate * 256 + k0 + kcell;
    BIAS[tid] = bih[jg] + bhh[jg];
  }
  for (int ci = tid; ci < 512; ci += 256) {
    const int bl = ci >> 4, kl = ci & 15;
    Cbuf[ci] = c0[(b0 + bl) * 256 + k0 + kl];
  }
  __syncthreads();

  const int r   = tid >> 3;            // staging row 0..31
  const int pb  = (tid & 7) * 8;       // staging chunk base
  const int arow = bsub * 16 + llo;    // A-frag row
  const unsigned abase = arow * 1024;
  const int asw = arow & 7;
  const int gb  = bsub * 16 + lhi * 4; // acc row base

  for (int t = 0; t < T_; ++t) {
    // ---- stage x_t || h_{t-1} into swizzled LDS ----
    if (t == 0) {
#pragma unroll
      for (int c = 0; c < 8; ++c) {
        const int p = pb + c, q = p ^ (r & 7);
        uint4 d;
        if (q < 32) {
          d = *(const uint4*)(xin + ((size_t)(b0 + r)) * 256 + q * 8);
        } else {
          const float* hs = h0 + (b0 + r) * 256 + (q - 32) * 8;
          float4 f0 = *(const float4*)hs, f1 = *(const float4*)(hs + 4);
          bf16x8 v = pack8(f0, f1);
          d = *(uint4*)&v;
        }
        *(uint4*)(Abuf + r * 1024 + p * 16) = d;
      }
    } else {
      const unsigned short* xsrc = xin  + ((size_t)t * B_ + b0) * 256;
      const unsigned short* hsrc = xout + ((size_t)(t - 1) * B_ + b0) * 256;
#pragma unroll
      for (int c = 0; c < 8; ++c) {
        const int p = pb + c, q = p ^ (r & 7);
        uint4 d = (q < 32) ? *(const uint4*)(xsrc + r * 256 + q * 8)
                           : *(const uint4*)(hsrc + r * 256 + (q - 32) * 8);
        *(uint4*)(Abuf + r * 1024 + p * 16) = d;
      }
    }
    __syncthreads();

    // ---- MFMA: g[32b x 64j] over K=512 ----
    f32x4 acc0 = {0.f, 0.f, 0.f, 0.f};
    f32x4 acc1 = {0.f, 0.f, 0.f, 0.f};
#pragma unroll
    for (int ks = 0; ks < 16; ++ks) {
      const int q = ks * 4 + lhi;
      bf16x8 a = *(const bf16x8*)(Abuf + abase + ((unsigned)(q ^ asw) << 4));
      acc0 = __builtin_amdgcn_mfma_f32_16x16x32_bf16(a, bw[0][ks], acc0, 0, 0, 0);
      acc1 = __builtin_amdgcn_mfma_f32_16x16x32_bf16(a, bw[1][ks], acc1, 0, 0, 0);
    }
#pragma unroll
    for (int rr = 0; rr < 4; ++rr) {
      Gbuf[(gb + rr) * 64 + jsub * 32 + llo]      = acc0[rr];
      Gbuf[(gb + rr) * 64 + jsub * 32 + 16 + llo] = acc1[rr];
    }
    __syncthreads();

    // ---- gate math (fp32), c in LDS, h -> global bf16 ----
    for (int ci = tid; ci < 512; ci += 256) {
      const int bl = ci >> 4, kl = ci & 15;
      const float* gp = &Gbuf[bl * 64 + kl * 4];
      float gi = gp[0] + BIAS[kl * 4 + 0];
      float gf = gp[1] + BIAS[kl * 4 + 1];
      float gg = gp[2] + BIAS[kl * 4 + 2];
      float go = gp[3] + BIAS[kl * 4 + 3];
      float iv = sigmoidf_(gi), fv = sigmoidf_(gf);
      float gv = tanhf_(gg),    ov = sigmoidf_(go);
      float cv = fv * Cbuf[ci] + iv * gv;
      Cbuf[ci] = cv;
      float hv = ov * tanhf_(cv);
      xout[((size_t)t * B_ + b0 + bl) * 256 + k0 + kl] = f2bf(hv);
      if (t == T_ - 1) {
        hN[(b0 + bl) * 256 + k0 + kl] = hv;
        cN[(b0 + bl) * 256 + k0 + kl] = cv;
      }
    }

    // ---- device-scope grid barrier (publish h, then sync 64 wgs) ----
    __syncthreads();
    if (tid == 0) {
      __threadfence();
      unsigned g = __hip_atomic_load(bar + 1, __ATOMIC_RELAXED, __HIP_MEMORY_SCOPE_AGENT);
      unsigned a = __hip_atomic_fetch_add(bar, 1u, __ATOMIC_ACQ_REL, __HIP_MEMORY_SCOPE_AGENT);
      if (a == NWG - 1) {
        __hip_atomic_store(bar, 0u, __ATOMIC_RELAXED, __HIP_MEMORY_SCOPE_AGENT);
        __hip_atomic_fetch_add(bar + 1, 1u, __ATOMIC_RELEASE, __HIP_MEMORY_SCOPE_AGENT);
      } else {
        while (__hip_atomic_load(bar + 1, __ATOMIC_ACQUIRE, __HIP_MEMORY_SCOPE_AGENT) == g)
          __builtin_amdgcn_s_sleep(1);
      }
    }
    __syncthreads();
  }
}

// ---------------------------------------------------------------------------
// FC: out[(b*T+t)][n] = h[t][b][:] . fc_w[n][:] + fc_b[n].  One wg per t.
// Waves split N (4 x 32n); each wave covers all 128 m rows; B-frags in regs.
__global__ __launch_bounds__(256, 1) void fc_kernel(
    const unsigned short* __restrict__ hbuf, const float* __restrict__ fc_w,
    const float* __restrict__ fc_b, float* __restrict__ out) {
  extern __shared__ char sm[];                 // [128 rows][256 bf16] = 64KB swizzled
  const int mt = blockIdx.x;                   // timestep
  {
    const int rr = threadIdx.x >> 1;
    const int pb = (threadIdx.x & 1) * 16;
#pragma unroll
    for (int c = 0; c < 16; ++c) {
      const int p = pb + c, q = p ^ (rr & 7);
      uint4 d = *(const uint4*)(hbuf + ((size_t)mt * B_ + rr) * 256 + q * 8);
      *(uint4*)(sm + rr * 512 + p * 16) = d;
    }
  }
  const int wv = threadIdx.x >> 6, lane = threadIdx.x & 63;
  const int lhi = lane >> 4, llo = lane & 15;

  bf16x8 bw[2][8];
#pragma unroll
  for (int nf = 0; nf < 2; ++nf) {
    const int n = wv * 32 + nf * 16 + llo;
#pragma unroll
    for (int ks = 0; ks < 8; ++ks) {
      const float* src = fc_w + n * 256 + ks * 32 + lhi * 8;
      float4 f0 = *(const float4*)src, f1 = *(const float4*)(src + 4);
      bw[nf][ks] = pack8(f0, f1);
    }
  }
  const float bias0 = fc_b[wv * 32 + llo];
  const float bias1 = fc_b[wv * 32 + 16 + llo];
  __syncthreads();

  f32x4 acc[8][2];
#pragma unroll
  for (int mf = 0; mf < 8; ++mf) {
    acc[mf][0] = (f32x4){0.f, 0.f, 0.f, 0.f};
    acc[mf][1] = (f32x4){0.f, 0.f, 0.f, 0.f};
  }
#pragma unroll
  for (int ks = 0; ks < 8; ++ks) {
    const int q = ks * 4 + lhi;
#pragma unroll
    for (int mf = 0; mf < 8; ++mf) {
      const int ar = mf * 16 + llo;
      bf16x8 a = *(const bf16x8*)(sm + ar * 512 + (unsigned)((q ^ (ar & 7)) << 4));
      acc[mf][0] = __builtin_amdgcn_mfma_f32_16x16x32_bf16(a, bw[0][ks], acc[mf][0], 0, 0, 0);
      acc[mf][1] = __builtin_amdgcn_mfma_f32_16x16x32_bf16(a, bw[1][ks], acc[mf][1], 0, 0, 0);
    }
  }
#pragma unroll
  for (int mf = 0; mf < 8; ++mf)
#pragma unroll
    for (int rr = 0; rr < 4; ++rr) {
      const int b = mf * 16 + lhi * 4 + rr;
      const size_t o = ((size_t)b * T_ + mt) * 128;
      out[o + wv * 32 + llo]      = acc[mf][0][rr] + bias0;
      out[o + wv * 32 + 16 + llo] = acc[mf][1][rr] + bias1;
    }
}

// ---------------------------------------------------------------------------
extern "C" void kernel_launch(void* const* d_in, const int* in_sizes, int n_in,
                              void* d_out, int out_size, void* d_ws, size_t ws_size,
                              hipStream_t stream) {
  (void)in_sizes; (void)n_in; (void)out_size; (void)ws_size;
  const int*   x     = (const int*)d_in[0];
  const float* h0    = (const float*)d_in[1];
  const float* c0    = (const float*)d_in[2];
  const float* table = (const float*)d_in[3];
  const float* Wih   = (const float*)d_in[4];
  const float* Whh   = (const float*)d_in[5];
  const float* bih   = (const float*)d_in[6];
  const float* bhh   = (const float*)d_in[7];
  const float* fcw   = (const float*)d_in[8];
  const float* fcb   = (const float*)d_in[9];
  float* out = (float*)d_out;
  char*  ws  = (char*)d_ws;

  unsigned short* xb0 = (unsigned short*)ws;                       // 64 MiB
  unsigned short* xb1 = (unsigned short*)(ws + (size_t)67108864);  // 64 MiB
  unsigned*       bar = (unsigned*)(ws + (size_t)2 * 67108864);

  float* hN = out + (size_t)16777216;   // logits: B*T*128
  float* cN = hN + 131072;              // 4*128*256

  init_kernel<<<dim3(1), dim3(64), 0, stream>>>(bar);
  embed_kernel<<<dim3(16384), dim3(256), 0, stream>>>(x, table, xb0);

  unsigned short* bufs[2] = {xb0, xb1};
  for (int l = 0; l < 4; ++l) {
    unsigned short* xi = bufs[l & 1];
    unsigned short* xo = bufs[(l + 1) & 1];
    lstm_scan<<<dim3(NWG), dim3(256), 0, stream>>>(
        xi, xo,
        Wih + (size_t)l * 262144, Whh + (size_t)l * 262144,
        bih + (size_t)l * 1024,   bhh + (size_t)l * 1024,
        h0 + (size_t)l * 32768,   c0 + (size_t)l * 32768,
        hN + (size_t)l * 32768,   cN + (size_t)l * 32768,
        bar);
  }
  fc_kernel<<<dim3(T_), dim3(256), 65536, stream>>>(bufs[0], fcw, fcb, out);
}

// Round 2
// 7657.783 us; speedup vs baseline: 4.0528x; 4.0528x over previous
//
#include <hip/hip_runtime.h>
#include <hip/hip_bf16.h>

// ---------------------------------------------------------------------------
// embed(gather) + 4x LSTM(256) pipelined in ONE persistent kernel + FC.
// Cross-wg sync: relaxed agent-scope atomics only (per-access sc1 coherence,
// no cache-wide inv/wb). 256 wgs = 4 layers x 4 b-tiles x 16 k-tiles.
// ---------------------------------------------------------------------------

#define B_ 128
#define T_ 1024
#define H_ 256
#define RING 16

typedef __attribute__((ext_vector_type(8))) short bf16x8;
typedef __attribute__((ext_vector_type(4))) float f32x4;

union U16B { uint4 v; unsigned long long q[2]; };

__device__ inline unsigned short f2bf(float f) {
  union { float f; unsigned u; } a; a.f = f;
  unsigned r = a.u + 0x7FFFu + ((a.u >> 16) & 1u);   // RNE
  return (unsigned short)(r >> 16);
}

__device__ inline bf16x8 pack8(float4 a, float4 b) {
  bf16x8 v;
  v[0] = (short)f2bf(a.x); v[1] = (short)f2bf(a.y);
  v[2] = (short)f2bf(a.z); v[3] = (short)f2bf(a.w);
  v[4] = (short)f2bf(b.x); v[5] = (short)f2bf(b.y);
  v[6] = (short)f2bf(b.z); v[7] = (short)f2bf(b.w);
  return v;
}

__device__ inline float sigmoidf_(float x) { return 1.0f / (1.0f + __expf(-x)); }
__device__ inline float tanhf_(float x) {
  float ax = fabsf(x);
  float e = __expf(-2.0f * ax);
  float t = (1.0f - e) / (1.0f + e);
  return copysignf(t, x);
}

__device__ inline unsigned long long ldu64(const void* p) {
  return __hip_atomic_load((const unsigned long long*)p, __ATOMIC_RELAXED,
                           __HIP_MEMORY_SCOPE_AGENT);
}
__device__ inline void stu64(void* p, unsigned long long v) {
  __hip_atomic_store((unsigned long long*)p, v, __ATOMIC_RELAXED,
                     __HIP_MEMORY_SCOPE_AGENT);
}
__device__ inline unsigned ldflag(const unsigned* p) {
  return __hip_atomic_load(p, __ATOMIC_RELAXED, __HIP_MEMORY_SCOPE_AGENT);
}
__device__ inline void stflag(unsigned* p, unsigned v) {
  __hip_atomic_store(p, v, __ATOMIC_RELAXED, __HIP_MEMORY_SCOPE_AGENT);
}

// ---------------------------------------------------------------------------
__global__ void init_kernel(unsigned* F) {
  F[blockIdx.x * 256 + threadIdx.x] = 0u;   // 4 blocks x 256 = 1024 u32
}

// ---------------------------------------------------------------------------
// wg = (l, bt, kt): layer, batch-tile(32 rows), cell-tile(16 cells = 64 gates).
// Weights in registers. Sync: flags F[(l*4+bt)*64 + kt] = steps completed.
__global__ __launch_bounds__(256, 1) void lstm_pipeline(
    const int* __restrict__ x, const float* __restrict__ table,
    const float* __restrict__ Wih_all, const float* __restrict__ Whh_all,
    const float* __restrict__ bih_all, const float* __restrict__ bhh_all,
    const float* __restrict__ h0_all, const float* __restrict__ c0_all,
    unsigned short* __restrict__ final_out,   // [T][B][256] bf16 (layer-3 h)
    unsigned short* ring,                     // [3][RING][B][256] bf16
    unsigned short* hx,                       // [4][2][B][256] bf16
    unsigned* F,                              // [16][64] u32
    float* __restrict__ hN, float* __restrict__ cN) {
  __shared__ uint4 AbufV[2048];          // [32 rows][512 bf16] swizzled, 32KB
  __shared__ float Gbuf[32 * 68];        // gate preacts, padded stride 68
  __shared__ float Cbuf[512];            // cell state [row*16 + kl]
  __shared__ float BIAS[64];
  char* Abuf = (char*)AbufV;

  const int tid  = threadIdx.x;
  const int wv   = tid >> 6, lane = tid & 63, lhi = lane >> 4, llo = lane & 15;
  const int wg   = blockIdx.x;
  const int l    = wg >> 6;
  const int bt   = (wg >> 4) & 3;
  const int kt   = wg & 15;
  const int b0   = bt * 32, k0 = kt * 16;
  const int jsub = wv & 1, bsub = wv >> 1;

  const float* Wih = Wih_all + (size_t)l * 262144;
  const float* Whh = Whh_all + (size_t)l * 262144;
  const float* bih = bih_all + (size_t)l * 1024;
  const float* bhh = bhh_all + (size_t)l * 1024;
  const float* h0  = h0_all + (size_t)l * 32768;
  const float* c0  = c0_all + (size_t)l * 32768;

  // ---- weights fp32 -> bf16 fragments in registers ----
  bf16x8 bw[2][16];
#pragma unroll
  for (int jf = 0; jf < 2; ++jf) {
    const int jlds  = jsub * 32 + jf * 16 + llo;     // 0..63, k-major (kcell*4+gate)
    const int kcell = jlds >> 2, gate = jlds & 3;
    const int jg    = gate * 256 + k0 + kcell;       // global gate row
#pragma unroll
    for (int ks = 0; ks < 16; ++ks) {
      const int q = ks * 4 + lhi;
      const float* src = (q < 32) ? (Wih + jg * 256 + q * 8)
                                  : (Whh + jg * 256 + (q - 32) * 8);
      float4 f0 = *(const float4*)src;
      float4 f1 = *(const float4*)(src + 4);
      bw[jf][ks] = pack8(f0, f1);
    }
  }

  if (tid < 64) {
    const int kcell = tid >> 2, gate = tid & 3;
    const int jg = gate * 256 + k0 + kcell;
    BIAS[tid] = bih[jg] + bhh[jg];
  }
  for (int ci = tid; ci < 512; ci += 256) {
    const int bl = ci >> 4, kl = ci & 15;
    Cbuf[ci] = c0[(b0 + bl) * 256 + k0 + kl];
  }
  __syncthreads();

  // ---- flag polling setup (wave 0, lane-parallel) ----
  unsigned* Fown = F + (l * 4 + bt) * 64;
  unsigned* Fup  = (l > 0) ? (F + ((l - 1) * 4 + bt) * 64) : Fown;
  unsigned* Fdn  = (l < 3) ? (F + ((l + 1) * 4 + bt) * 64) : Fown;
  const unsigned* myfp = Fown + llo;
  int  toff = 0;
  bool active = true;
  if (lhi == 0)      { myfp = Fown + llo; toff = 0;           active = true; }
  else if (lhi == 1) { myfp = Fup + llo;  toff = 1;           active = (l > 0); }
  else if (lhi == 2) { myfp = Fdn + llo;  toff = -(RING - 1); active = (l < 3); }
  else               { active = false; }

  const unsigned short* xring = ring + (size_t)((l > 0) ? (l - 1) : 0) * RING * B_ * 256;
  unsigned short* oring = ring + (size_t)((l < 3) ? l : 0) * RING * B_ * 256;
  unsigned short* hxl   = hx + (size_t)l * 2 * B_ * 256;

  const int r  = tid >> 3;             // staging row 0..31
  const int pb = (tid & 7) * 8;        // staging 16B-chunk base
  const int arow = bsub * 16 + llo;
  const unsigned abase = arow * 1024;
  const int asw = arow & 7;
  const int gb  = bsub * 16 + lhi * 4;

  for (int t = 0; t < T_; ++t) {
    // ---- poll: own h_{t-1}, upstream x_t, downstream ring space ----
    if (wv == 0) {
      const int target = t + toff;
      for (;;) {
        int v = active ? (int)ldflag(myfp) : 0x7fffffff;
        if (__all(v >= target)) break;
        __builtin_amdgcn_s_sleep(2);
      }
    }
    __syncthreads();

    // ---- stage A = [x_t || h_{t-1}] into swizzled LDS ----
    uint4 stg[8];
    const int idxr = (l == 0) ? x[(b0 + r) * T_ + t] : 0;
#pragma unroll
    for (int c = 0; c < 8; ++c) {
      const int p = pb + c, q = p ^ (r & 7);
      uint4 d;
      if (q < 32) {                       // x half
        if (l == 0) {
          const float* src = table + idxr * 256 + q * 8;
          float4 f0 = *(const float4*)src, f1 = *(const float4*)(src + 4);
          bf16x8 v = pack8(f0, f1); d = *(uint4*)&v;
        } else {
          const unsigned short* sp =
              xring + ((size_t)(t & (RING - 1)) * B_ + b0 + r) * 256 + q * 8;
          U16B u; u.q[0] = ldu64(sp); u.q[1] = ldu64(sp + 4); d = u.v;
        }
      } else {                            // h half
        if (t == 0) {
          const float* hs = h0 + (b0 + r) * 256 + (q - 32) * 8;
          float4 f0 = *(const float4*)hs, f1 = *(const float4*)(hs + 4);
          bf16x8 v = pack8(f0, f1); d = *(uint4*)&v;
        } else {
          const unsigned short* sp =
              hxl + ((size_t)((t - 1) & 1) * B_ + b0 + r) * 256 + (q - 32) * 8;
          U16B u; u.q[0] = ldu64(sp); u.q[1] = ldu64(sp + 4); d = u.v;
        }
      }
      stg[c] = d;
    }
#pragma unroll
    for (int c = 0; c < 8; ++c)
      *(uint4*)(Abuf + r * 1024 + (pb + c) * 16) = stg[c];
    __syncthreads();

    // ---- MFMA: g[32b x 64j] over K=512 ----
    f32x4 acc0 = {0.f, 0.f, 0.f, 0.f};
    f32x4 acc1 = {0.f, 0.f, 0.f, 0.f};
#pragma unroll
    for (int ks = 0; ks < 16; ++ks) {
      const int q = ks * 4 + lhi;
      bf16x8 a = *(const bf16x8*)(Abuf + abase + ((unsigned)(q ^ asw) << 4));
      acc0 = __builtin_amdgcn_mfma_f32_16x16x32_bf16(a, bw[0][ks], acc0, 0, 0, 0);
      acc1 = __builtin_amdgcn_mfma_f32_16x16x32_bf16(a, bw[1][ks], acc1, 0, 0, 0);
    }
#pragma unroll
    for (int rr = 0; rr < 4; ++rr) {
      Gbuf[(gb + rr) * 68 + jsub * 32 + llo]      = acc0[rr];
      Gbuf[(gb + rr) * 68 + jsub * 32 + 16 + llo] = acc1[rr];
    }
    __syncthreads();

    // ---- gate math: 128 threads x 4 cells ----
    if (tid < 128) {
      const int row = tid >> 2, quad = tid & 3;
      float4 c4 = *(const float4*)&Cbuf[row * 16 + quad * 4];
      float cin[4] = {c4.x, c4.y, c4.z, c4.w};
      float hv[4], cv[4];
#pragma unroll
      for (int j = 0; j < 4; ++j) {
        const int kl = quad * 4 + j;
        float4 g4 = *(const float4*)&Gbuf[row * 68 + kl * 4];
        float gi = g4.x + BIAS[kl * 4 + 0];
        float gf = g4.y + BIAS[kl * 4 + 1];
        float gg = g4.z + BIAS[kl * 4 + 2];
        float go = g4.w + BIAS[kl * 4 + 3];
        float iv = sigmoidf_(gi), fv = sigmoidf_(gf);
        float gv = tanhf_(gg),    ov = sigmoidf_(go);
        cv[j] = fv * cin[j] + iv * gv;
        hv[j] = ov * tanhf_(cv[j]);
      }
      *(float4*)&Cbuf[row * 16 + quad * 4] = make_float4(cv[0], cv[1], cv[2], cv[3]);

      unsigned long long hq =
          (unsigned long long)f2bf(hv[0]) |
          ((unsigned long long)f2bf(hv[1]) << 16) |
          ((unsigned long long)f2bf(hv[2]) << 32) |
          ((unsigned long long)f2bf(hv[3]) << 48);
      // own-group h exchange (double buffered)
      stu64(hxl + ((size_t)(t & 1) * B_ + b0 + row) * 256 + k0 + quad * 4, hq);
      // downstream: ring (l<3) or final buffer (l==3)
      if (l < 3)
        stu64(oring + ((size_t)(t & (RING - 1)) * B_ + b0 + row) * 256 + k0 + quad * 4, hq);
      else
        *(unsigned long long*)(final_out +
            ((size_t)t * B_ + b0 + row) * 256 + k0 + quad * 4) = hq;

      if (t == T_ - 1) {
        *(float4*)(hN + ((size_t)(l * B_ + b0 + row)) * 256 + k0 + quad * 4) =
            make_float4(hv[0], hv[1], hv[2], hv[3]);
        *(float4*)(cN + ((size_t)(l * B_ + b0 + row)) * 256 + k0 + quad * 4) =
            make_float4(cv[0], cv[1], cv[2], cv[3]);
      }
    }
    __syncthreads();   // drains all waves' stores (vmcnt(0) before s_barrier)

    if (tid == 0) stflag(&Fown[kt], (unsigned)(t + 1));
  }
}

// ---------------------------------------------------------------------------
// FC: out[(b*T+t)][n] = h[t][b][:] . fc_w[n][:] + fc_b[n].  One wg per t.
__global__ __launch_bounds__(256, 1) void fc_kernel(
    const unsigned short* __restrict__ hbuf, const float* __restrict__ fc_w,
    const float* __restrict__ fc_b, float* __restrict__ out) {
  extern __shared__ char sm[];                 // [128 rows][256 bf16] swizzled
  const int mt = blockIdx.x;
  {
    const int rr = threadIdx.x >> 1;
    const int pb = (threadIdx.x & 1) * 16;
#pragma unroll
    for (int c = 0; c < 16; ++c) {
      const int p = pb + c, q = p ^ (rr & 7);
      uint4 d = *(const uint4*)(hbuf + ((size_t)mt * B_ + rr) * 256 + q * 8);
      *(uint4*)(sm + rr * 512 + p * 16) = d;
    }
  }
  const int wv = threadIdx.x >> 6, lane = threadIdx.x & 63;
  const int lhi = lane >> 4, llo = lane & 15;

  bf16x8 bw[2][8];
#pragma unroll
  for (int nf = 0; nf < 2; ++nf) {
    const int n = wv * 32 + nf * 16 + llo;
#pragma unroll
    for (int ks = 0; ks < 8; ++ks) {
      const float* src = fc_w + n * 256 + ks * 32 + lhi * 8;
      float4 f0 = *(const float4*)src, f1 = *(const float4*)(src + 4);
      bw[nf][ks] = pack8(f0, f1);
    }
  }
  const float bias0 = fc_b[wv * 32 + llo];
  const float bias1 = fc_b[wv * 32 + 16 + llo];
  __syncthreads();

  f32x4 acc[8][2];
#pragma unroll
  for (int mf = 0; mf < 8; ++mf) {
    acc[mf][0] = (f32x4){0.f, 0.f, 0.f, 0.f};
    acc[mf][1] = (f32x4){0.f, 0.f, 0.f, 0.f};
  }
#pragma unroll
  for (int ks = 0; ks < 8; ++ks) {
    const int q = ks * 4 + lhi;
#pragma unroll
    for (int mf = 0; mf < 8; ++mf) {
      const int ar = mf * 16 + llo;
      bf16x8 a = *(const bf16x8*)(sm + ar * 512 + (unsigned)((q ^ (ar & 7)) << 4));
      acc[mf][0] = __builtin_amdgcn_mfma_f32_16x16x32_bf16(a, bw[0][ks], acc[mf][0], 0, 0, 0);
      acc[mf][1] = __builtin_amdgcn_mfma_f32_16x16x32_bf16(a, bw[1][ks], acc[mf][1], 0, 0, 0);
    }
  }
#pragma unroll
  for (int mf = 0; mf < 8; ++mf)
#pragma unroll
    for (int rr = 0; rr < 4; ++rr) {
      const int b = mf * 16 + lhi * 4 + rr;
      const size_t o = ((size_t)b * T_ + mt) * 128;
      out[o + wv * 32 + llo]      = acc[mf][0][rr] + bias0;
      out[o + wv * 32 + 16 + llo] = acc[mf][1][rr] + bias1;
    }
}

// ---------------------------------------------------------------------------
extern "C" void kernel_launch(void* const* d_in, const int* in_sizes, int n_in,
                              void* d_out, int out_size, void* d_ws, size_t ws_size,
                              hipStream_t stream) {
  (void)in_sizes; (void)n_in; (void)out_size; (void)ws_size;
  const int*   x     = (const int*)d_in[0];
  const float* h0    = (const float*)d_in[1];
  const float* c0    = (const float*)d_in[2];
  const float* table = (const float*)d_in[3];
  const float* Wih   = (const float*)d_in[4];
  const float* Whh   = (const float*)d_in[5];
  const float* bih   = (const float*)d_in[6];
  const float* bhh   = (const float*)d_in[7];
  const float* fcw   = (const float*)d_in[8];
  const float* fcb   = (const float*)d_in[9];
  float* out = (float*)d_out;
  char*  ws  = (char*)d_ws;

  unsigned short* final_out = (unsigned short*)ws;                        // 64 MiB
  unsigned short* ring      = (unsigned short*)(ws + 67108864);           // 3 MiB
  unsigned short* hx        = (unsigned short*)(ws + 67108864 + 3145728); // 512 KiB
  unsigned*       F         = (unsigned*)(ws + 67108864 + 3145728 + 524288);

  float* hN = out + (size_t)16777216;   // logits: B*T*128
  float* cN = hN + 131072;              // 4*128*256

  init_kernel<<<dim3(4), dim3(256), 0, stream>>>(F);
  lstm_pipeline<<<dim3(256), dim3(256), 0, stream>>>(
      x, table, Wih, Whh, bih, bhh, h0, c0, final_out, ring, hx, F, hN, cN);
  fc_kernel<<<dim3(T_), dim3(256), 65536, stream>>>(final_out, fcw, fcb, out);
}

// Round 10
// 4849.594 us; speedup vs baseline: 6.3996x; 1.5791x over previous
//
#include <hip/hip_runtime.h>
#include <hip/hip_bf16.h>

// ---------------------------------------------------------------------------
// One persistent kernel: embed-gather + 4x LSTM(256) + FC(128), B=128 T=1024.
// 64 REC wgs (4 layers x 4 batch-tiles x 4 cell-tiles, 512 thr) + 16 FC wgs.
// Critical path sync: tag-embedded fp32 h-exchange, DOUBLE-BUFFERED by t&1
// (tag LSB = (t>>1)&1; LSB is dropped by bf16 truncation so numerics are
// unchanged). Single-buffer version raced: writer could overwrite t-data
// with t+1-data before a stalled consumer read it (R6 failure, absmax 468).
// Inter-layer x and FC inputs go through bf16 rings with batched flags.
// All spin loops are BOUNDED (~1ms) so a protocol bug terminates with wrong
// data + counters instead of hanging the container.
// ---------------------------------------------------------------------------

#define B_ 128
#define T_ 1024
#define HR 64          // ring depth (steps)
#define SPIN_LIMIT 32768

typedef __attribute__((ext_vector_type(8))) short bf16x8;
typedef __attribute__((ext_vector_type(4))) float f32x4;
typedef unsigned long long u64;

#define MFMA16 __builtin_amdgcn_mfma_f32_16x16x32_bf16

__device__ inline unsigned short bf_bits(unsigned u) {      // RNE fp32->bf16
  unsigned r = u + 0x7FFFu + ((u >> 16) & 1u);
  return (unsigned short)(r >> 16);
}
__device__ inline unsigned short f2bf(float f) {
  union { float f; unsigned u; } a; a.f = f;
  return bf_bits(a.u);
}
__device__ inline bf16x8 pack8(float4 a, float4 b) {
  bf16x8 v;
  v[0] = (short)f2bf(a.x); v[1] = (short)f2bf(a.y);
  v[2] = (short)f2bf(a.z); v[3] = (short)f2bf(a.w);
  v[4] = (short)f2bf(b.x); v[5] = (short)f2bf(b.y);
  v[6] = (short)f2bf(b.z); v[7] = (short)f2bf(b.w);
  return v;
}
__device__ inline float sigmoidf_(float x) { return 1.0f / (1.0f + __expf(-x)); }
__device__ inline float tanhf_(float x) {
  float ax = fabsf(x);
  float e = __expf(-2.0f * ax);
  float t = (1.0f - e) / (1.0f + e);
  return copysignf(t, x);
}

__device__ inline u64 ldu64(const void* p) {
  return __hip_atomic_load((const u64*)p, __ATOMIC_RELAXED, __HIP_MEMORY_SCOPE_AGENT);
}
__device__ inline void stu64(void* p, u64 v) {
  __hip_atomic_store((u64*)p, v, __ATOMIC_RELAXED, __HIP_MEMORY_SCOPE_AGENT);
}
__device__ inline unsigned ldflag(const unsigned* p) {
  return __hip_atomic_load(p, __ATOMIC_RELAXED, __HIP_MEMORY_SCOPE_AGENT);
}
__device__ inline void stflag(unsigned* p, unsigned v) {
  __hip_atomic_store(p, v, __ATOMIC_RELAXED, __HIP_MEMORY_SCOPE_AGENT);
}

// ---------------------------------------------------------------------------
__global__ void init_kernel(unsigned* HEXu, unsigned* F_h, unsigned* F_fc) {
  const int i = blockIdx.x * 512 + threadIdx.x;   // 512 x 512 = 262144
  HEXu[i] = 1u;                                   // tag bit 1 != first-write tag 0
  if (i < 64) F_h[i] = 0u;
  if (i < 16) F_fc[i] = 0u;
}

// ---------------------------------------------------------------------------
__global__ __launch_bounds__(512, 2) void mega(
    const int* __restrict__ x, const float* __restrict__ table,
    const float* __restrict__ Wih_all, const float* __restrict__ Whh_all,
    const float* __restrict__ bih_all, const float* __restrict__ bhh_all,
    const float* __restrict__ h0_all, const float* __restrict__ c0_all,
    const float* __restrict__ fcw, const float* __restrict__ fcb,
    float* __restrict__ out, float* __restrict__ hN, float* __restrict__ cN,
    unsigned short* ring, float* HEX, unsigned* F_h, unsigned* F_fc) {
  __shared__ char Ab[32 * 512];      // [32 rows][256 bf16], 16B-chunk XOR swizzle
  __shared__ float Gb[32 * 260];     // gate preacts [row][cell*4+gate]

  const int tid = threadIdx.x;
  const int wv = tid >> 6, lane = tid & 63, lhi = lane >> 4, llo = lane & 15;
  const int sr = tid >> 4, sq = tid & 15;   // staging/gate mapping: row, quad

  if (blockIdx.x < 64) {
    // =============================== REC ===================================
    const int l = blockIdx.x >> 4, bt = (blockIdx.x >> 2) & 3, ct = blockIdx.x & 3;
    const int b0 = bt * 32;
    const float* Wih = Wih_all + (size_t)l * 262144;
    const float* Whh = Whh_all + (size_t)l * 262144;

    // weights: wg owns 64 cells (256 gate rows), K=512, bf16 frags in regs
    bf16x8 bw[2][16];
#pragma unroll
    for (int ni = 0; ni < 2; ++ni) {
      const int jloc = wv * 32 + ni * 16 + llo;      // 0..255 (gate-major)
      const int gate = jloc >> 6, cl = jloc & 63;
      const int jg = gate * 256 + ct * 64 + cl;
#pragma unroll
      for (int ks = 0; ks < 16; ++ks) {
        const int k0 = (ks * 4 + lhi) * 8;
        const float* src = (k0 < 256) ? (Wih + jg * 256 + k0)
                                      : (Whh + jg * 256 + (k0 - 256));
        bw[ni][ks] = pack8(*(const float4*)src, *(const float4*)(src + 4));
      }
    }

    float bias[4][4];                                // [cell e][gate]
#pragma unroll
    for (int e = 0; e < 4; ++e)
#pragma unroll
      for (int g = 0; g < 4; ++g) {
        const int jg = g * 256 + ct * 64 + sq * 4 + e;
        bias[e][g] = bih_all[l * 1024 + jg] + bhh_all[l * 1024 + jg];
      }

    float creg[4];
    {
      float4 c4 = *(const float4*)(c0_all + (size_t)l * 32768 +
                                   (b0 + sr) * 256 + ct * 64 + sq * 4);
      creg[0] = c4.x; creg[1] = c4.y; creg[2] = c4.z; creg[3] = c4.w;
    }

    unsigned short* oring = ring + (size_t)l * HR * B_ * 256;
    const unsigned short* xring = ring + (size_t)(l > 0 ? l - 1 : 0) * HR * B_ * 256;
    // HEX layout: [16 groups][4 ct][2 buffers][32 sr][64 f]
    float* hexg = HEX + (size_t)(l * 4 + bt) * 16384;
    unsigned* Fown = F_h + (l * 4 + bt) * 4;
    unsigned* Fup  = F_h + ((l > 0 ? l - 1 : 0) * 4 + bt) * 4;
    unsigned* Fdn  = (l < 3) ? (F_h + ((l + 1) * 4 + bt) * 4) : (F_fc + bt * 4);

    const int w0 = (ct + 1) & 3, w1 = (ct + 2) & 3, w2 = (ct + 3) & 3;
    const float* s0 = hexg + w0 * 4096 + sr * 64 + sq * 4;
    const float* s1 = hexg + w1 * 4096 + sr * 64 + sq * 4;
    const float* s2 = hexg + w2 * 4096 + sr * 64 + sq * 4;

    int xseen = (l == 0) ? 0x7fffffff : 0;
    u64 hreg = 0;

    for (int t = 0; t < T_; ++t) {
      // ---- back-pressure on downstream ring consumption (every 8 steps) ----
      if ((t & 7) == 0 && t >= 64) {
        const int need = t - 56;
        int guard = 0;
        for (;;) {
          int m = (int)ldflag(Fdn + 0);
          int m1 = (int)ldflag(Fdn + 1); if (m1 < m) m = m1;
          int m2 = (int)ldflag(Fdn + 2); if (m2 < m) m = m2;
          int m3 = (int)ldflag(Fdn + 3); if (m3 < m) m = m3;
          if (m >= need || ++guard > SPIN_LIMIT) break;
          __builtin_amdgcn_s_sleep(16);
        }
      }
      // ---- upstream x availability (batched flags, cached) ----
      if (xseen < t + 1) {
        int guard = 0;
        for (;;) {
          int m = (int)ldflag(Fup + 0);
          int m1 = (int)ldflag(Fup + 1); if (m1 < m) m = m1;
          int m2 = (int)ldflag(Fup + 2); if (m2 < m) m = m2;
          int m3 = (int)ldflag(Fup + 3); if (m3 < m) m = m3;
          if (m >= t + 1) { xseen = m; break; }
          if (++guard > SPIN_LIMIT) break;
          __builtin_amdgcn_s_sleep(2);
        }
      }

      // ---- phase0: stage x_t into Ab ----
      if (l == 0) {
        const int tok = x[(b0 + sr) * T_ + t];
        const float* tb = table + tok * 256;
#pragma unroll
        for (int hh = 0; hh < 2; ++hh) {
          const int cx = sq + hh * 16;
          bf16x8 v = pack8(*(const float4*)(tb + cx * 8),
                           *(const float4*)(tb + cx * 8 + 4));
          *(uint4*)(Ab + sr * 512 + ((cx ^ (sr & 7)) << 4)) = *(uint4*)&v;
        }
      } else {
        const unsigned short* sp = xring + ((size_t)(t & (HR - 1)) * B_ + b0 + sr) * 256;
#pragma unroll
        for (int hh = 0; hh < 2; ++hh) {
          const int cx = sq + hh * 16;
          u64 q0 = ldu64(sp + cx * 8);
          u64 q1 = ldu64(sp + cx * 8 + 4);
          uint4 d; d.x = (unsigned)q0; d.y = (unsigned)(q0 >> 32);
          d.z = (unsigned)q1; d.w = (unsigned)(q1 >> 32);
          *(uint4*)(Ab + sr * 512 + ((cx ^ (sr & 7)) << 4)) = d;
        }
      }
      __syncthreads();   // bar A
      if ((t & 3) == 0 && t > 0 && tid == 0) stflag(Fown + ct, (unsigned)t);

      // ---- phase1: MFMA pass 1 (x contribution, K 0..255) ----
      f32x4 acc[2][2];
#pragma unroll
      for (int mi = 0; mi < 2; ++mi)
#pragma unroll
        for (int ni = 0; ni < 2; ++ni) acc[mi][ni] = (f32x4){0.f, 0.f, 0.f, 0.f};
      {
        const int r0 = llo, r1 = 16 + llo;
#pragma unroll
        for (int ks = 0; ks < 8; ++ks) {
          const int q = ks * 4 + lhi;
          bf16x8 a0 = *(const bf16x8*)(Ab + r0 * 512 + ((q ^ (r0 & 7)) << 4));
          bf16x8 a1 = *(const bf16x8*)(Ab + r1 * 512 + ((q ^ (r1 & 7)) << 4));
          acc[0][0] = MFMA16(a0, bw[0][ks], acc[0][0], 0, 0, 0);
          acc[0][1] = MFMA16(a0, bw[1][ks], acc[0][1], 0, 0, 0);
          acc[1][0] = MFMA16(a1, bw[0][ks], acc[1][0], 0, 0, 0);
          acc[1][1] = MFMA16(a1, bw[1][ks], acc[1][1], 0, 0, 0);
        }
      }
      __syncthreads();   // bar B

      // ---- phase2: stage h_{t-1} (own from reg; partners via tag poll) ----
      if (t == 0) {
        const float* h0 = h0_all + (size_t)l * 32768;
#pragma unroll
        for (int wq = 0; wq < 4; ++wq) {
          float4 f = *(const float4*)(h0 + (b0 + sr) * 256 + wq * 64 + sq * 4);
          u64 hq = (u64)f2bf(f.x) | ((u64)f2bf(f.y) << 16) |
                   ((u64)f2bf(f.z) << 32) | ((u64)f2bf(f.w) << 48);
          *(u64*)(Ab + sr * 512 + (((wq * 8 + (sq >> 1)) ^ (sr & 7)) << 4) + (sq & 1) * 8) = hq;
        }
      } else {
        *(u64*)(Ab + sr * 512 + (((ct * 8 + (sq >> 1)) ^ (sr & 7)) << 4) + (sq & 1) * 8) = hreg;
        const int boff = ((t - 1) & 1) * 2048;            // buffer of step t-1
        const unsigned par = (unsigned)(((t - 1) >> 1) & 1);  // tag of step t-1
        unsigned pa0, pa1, pa2, pa3, pb0, pb1, pb2, pb3, pc0, pc1, pc2, pc3;
        int guard = 0;
        for (;;) {
          u64 a0 = ldu64(s0 + boff), a1 = ldu64(s0 + boff + 2);
          u64 b0q = ldu64(s1 + boff), b1q = ldu64(s1 + boff + 2);
          u64 c0q = ldu64(s2 + boff), c1q = ldu64(s2 + boff + 2);
          pa0 = (unsigned)a0;  pa1 = (unsigned)(a0 >> 32);
          pa2 = (unsigned)a1;  pa3 = (unsigned)(a1 >> 32);
          pb0 = (unsigned)b0q; pb1 = (unsigned)(b0q >> 32);
          pb2 = (unsigned)b1q; pb3 = (unsigned)(b1q >> 32);
          pc0 = (unsigned)c0q; pc1 = (unsigned)(c0q >> 32);
          pc2 = (unsigned)c1q; pc3 = (unsigned)(c1q >> 32);
          unsigned bad = ((pa0 ^ par) | (pa1 ^ par) | (pa2 ^ par) | (pa3 ^ par) |
                          (pb0 ^ par) | (pb1 ^ par) | (pb2 ^ par) | (pb3 ^ par) |
                          (pc0 ^ par) | (pc1 ^ par) | (pc2 ^ par) | (pc3 ^ par)) & 1u;
          if (!bad || ++guard > SPIN_LIMIT) break;
          __builtin_amdgcn_s_sleep(1);
        }
        u64 hq0 = (u64)bf_bits(pa0) | ((u64)bf_bits(pa1) << 16) |
                  ((u64)bf_bits(pa2) << 32) | ((u64)bf_bits(pa3) << 48);
        u64 hq1 = (u64)bf_bits(pb0) | ((u64)bf_bits(pb1) << 16) |
                  ((u64)bf_bits(pb2) << 32) | ((u64)bf_bits(pb3) << 48);
        u64 hq2 = (u64)bf_bits(pc0) | ((u64)bf_bits(pc1) << 16) |
                  ((u64)bf_bits(pc2) << 32) | ((u64)bf_bits(pc3) << 48);
        *(u64*)(Ab + sr * 512 + (((w0 * 8 + (sq >> 1)) ^ (sr & 7)) << 4) + (sq & 1) * 8) = hq0;
        *(u64*)(Ab + sr * 512 + (((w1 * 8 + (sq >> 1)) ^ (sr & 7)) << 4) + (sq & 1) * 8) = hq1;
        *(u64*)(Ab + sr * 512 + (((w2 * 8 + (sq >> 1)) ^ (sr & 7)) << 4) + (sq & 1) * 8) = hq2;
      }
      __syncthreads();   // bar C

      // ---- phase3: MFMA pass 2 (h contribution, K 256..511) + Gb write ----
      {
        const int r0 = llo, r1 = 16 + llo;
#pragma unroll
        for (int ks = 0; ks < 8; ++ks) {
          const int q = ks * 4 + lhi;
          bf16x8 a0 = *(const bf16x8*)(Ab + r0 * 512 + ((q ^ (r0 & 7)) << 4));
          bf16x8 a1 = *(const bf16x8*)(Ab + r1 * 512 + ((q ^ (r1 & 7)) << 4));
          acc[0][0] = MFMA16(a0, bw[0][ks + 8], acc[0][0], 0, 0, 0);
          acc[0][1] = MFMA16(a0, bw[1][ks + 8], acc[0][1], 0, 0, 0);
          acc[1][0] = MFMA16(a1, bw[0][ks + 8], acc[1][0], 0, 0, 0);
          acc[1][1] = MFMA16(a1, bw[1][ks + 8], acc[1][1], 0, 0, 0);
        }
      }
#pragma unroll
      for (int mi = 0; mi < 2; ++mi)
#pragma unroll
        for (int ni = 0; ni < 2; ++ni) {
          const int jloc = wv * 32 + ni * 16 + llo;
          const int gate = jloc >> 6, cl = jloc & 63;
#pragma unroll
          for (int rr = 0; rr < 4; ++rr)
            Gb[(mi * 16 + lhi * 4 + rr) * 260 + cl * 4 + gate] = acc[mi][ni][rr];
        }
      __syncthreads();   // bar D

      // ---- phase4: gate math + h/c update + stores ----
      const unsigned tag_t = (unsigned)((t >> 1) & 1);
      unsigned hb[4]; float hvf[4];
#pragma unroll
      for (int e = 0; e < 4; ++e) {
        float4 g4 = *(const float4*)&Gb[sr * 260 + (sq * 4 + e) * 4];
        float gi = g4.x + bias[e][0];
        float gf = g4.y + bias[e][1];
        float gg = g4.z + bias[e][2];
        float go = g4.w + bias[e][3];
        float iv = sigmoidf_(gi), fv = sigmoidf_(gf);
        float gv = tanhf_(gg),   ov = sigmoidf_(go);
        creg[e] = fv * creg[e] + iv * gv;
        hvf[e] = ov * tanhf_(creg[e]);
        union { float f; unsigned u; } uu; uu.f = hvf[e];
        hb[e] = (uu.u & ~1u) | tag_t;                 // tag in mantissa LSB
      }
      float* slot = hexg + ct * 4096 + (t & 1) * 2048 + sr * 64 + sq * 4;
      stu64(slot,     (u64)hb[0] | ((u64)hb[1] << 32));
      stu64(slot + 2, (u64)hb[2] | ((u64)hb[3] << 32));
      hreg = (u64)bf_bits(hb[0]) | ((u64)bf_bits(hb[1]) << 16) |
             ((u64)bf_bits(hb[2]) << 32) | ((u64)bf_bits(hb[3]) << 48);
      stu64(oring + ((size_t)(t & (HR - 1)) * B_ + b0 + sr) * 256 + ct * 64 + sq * 4, hreg);
      if (t == T_ - 1) {
        *(float4*)(hN + ((size_t)l * B_ + b0 + sr) * 256 + ct * 64 + sq * 4) =
            make_float4(hvf[0], hvf[1], hvf[2], hvf[3]);
        *(float4*)(cN + ((size_t)l * B_ + b0 + sr) * 256 + ct * 64 + sq * 4) =
            make_float4(creg[0], creg[1], creg[2], creg[3]);
      }
    }
    __syncthreads();
    if (tid == 0) stflag(Fown + ct, (unsigned)T_);

  } else {
    // =============================== FC ====================================
    const int f = blockIdx.x - 64, fbt = f & 3, ph = f >> 2;
    const int b0 = fbt * 32;
    const int mi = wv >> 2, nw = wv & 3, n0 = nw * 32;

    bf16x8 bwf[2][8];
#pragma unroll
    for (int ni = 0; ni < 2; ++ni) {
      const int n = n0 + ni * 16 + llo;
#pragma unroll
      for (int ks = 0; ks < 8; ++ks) {
        const int k0 = (ks * 4 + lhi) * 8;
        const float* src = fcw + n * 256 + k0;
        bwf[ni][ks] = pack8(*(const float4*)src, *(const float4*)(src + 4));
      }
    }
    const float fb0 = fcb[n0 + llo], fb1 = fcb[n0 + 16 + llo];
    const unsigned short* r3 = ring + (size_t)3 * HR * B_ * 256;
    unsigned* F3 = F_h + (3 * 4 + fbt) * 4;
    int seen = 0;

    for (int t = ph; t < T_; t += 4) {
      if (seen < t + 1) {
        int guard = 0;
        for (;;) {
          int m = (int)ldflag(F3 + 0);
          int m1 = (int)ldflag(F3 + 1); if (m1 < m) m = m1;
          int m2 = (int)ldflag(F3 + 2); if (m2 < m) m = m2;
          int m3 = (int)ldflag(F3 + 3); if (m3 < m) m = m3;
          if (m >= t + 1) { seen = m; break; }
          if (++guard > SPIN_LIMIT) break;
          __builtin_amdgcn_s_sleep(8);
        }
      }
      const unsigned short* sp = r3 + ((size_t)(t & (HR - 1)) * B_ + b0 + sr) * 256;
#pragma unroll
      for (int hh = 0; hh < 2; ++hh) {
        const int cx = sq + hh * 16;
        u64 q0 = ldu64(sp + cx * 8);
        u64 q1 = ldu64(sp + cx * 8 + 4);
        uint4 d; d.x = (unsigned)q0; d.y = (unsigned)(q0 >> 32);
        d.z = (unsigned)q1; d.w = (unsigned)(q1 >> 32);
        *(uint4*)(Ab + sr * 512 + ((cx ^ (sr & 7)) << 4)) = d;
      }
      __syncthreads();

      f32x4 acc0 = {0.f, 0.f, 0.f, 0.f}, acc1 = {0.f, 0.f, 0.f, 0.f};
      const int arow = mi * 16 + llo;
#pragma unroll
      for (int ks = 0; ks < 8; ++ks) {
        bf16x8 a = *(const bf16x8*)(Ab + arow * 512 + (((ks * 4 + lhi) ^ (arow & 7)) << 4));
        acc0 = MFMA16(a, bwf[0][ks], acc0, 0, 0, 0);
        acc1 = MFMA16(a, bwf[1][ks], acc1, 0, 0, 0);
      }
#pragma unroll
      for (int rr = 0; rr < 4; ++rr) {
        const int row = mi * 16 + lhi * 4 + rr;
        const size_t o = ((size_t)(b0 + row) * T_ + t) * 128;
        out[o + n0 + llo]      = acc0[rr] + fb0;
        out[o + n0 + 16 + llo] = acc1[rr] + fb1;
      }
      __syncthreads();
      if (tid == 0) stflag(F_fc + fbt * 4 + ph, (unsigned)(t + 1));
    }
  }
}

// ---------------------------------------------------------------------------
extern "C" void kernel_launch(void* const* d_in, const int* in_sizes, int n_in,
                              void* d_out, int out_size, void* d_ws, size_t ws_size,
                              hipStream_t stream) {
  (void)in_sizes; (void)n_in; (void)out_size; (void)ws_size;
  const int*   x     = (const int*)d_in[0];
  const float* h0    = (const float*)d_in[1];
  const float* c0    = (const float*)d_in[2];
  const float* table = (const float*)d_in[3];
  const float* Wih   = (const float*)d_in[4];
  const float* Whh   = (const float*)d_in[5];
  const float* bih   = (const float*)d_in[6];
  const float* bhh   = (const float*)d_in[7];
  const float* fcw   = (const float*)d_in[8];
  const float* fcb   = (const float*)d_in[9];
  float* out = (float*)d_out;
  char*  ws  = (char*)d_ws;

  unsigned short* ring = (unsigned short*)ws;                       // 16 MiB
  float*    HEXf = (float*)(ws + (size_t)16777216);                 // 1 MiB
  unsigned* F_h  = (unsigned*)(ws + (size_t)16777216 + 1048576);    // 64 u32
  unsigned* F_fc = (unsigned*)(ws + (size_t)16777216 + 1048576 + 256);

  float* hN = out + (size_t)16777216;   // logits: B*T*128
  float* cN = hN + 131072;              // 4*128*256

  init_kernel<<<dim3(512), dim3(512), 0, stream>>>((unsigned*)HEXf, F_h, F_fc);
  mega<<<dim3(80), dim3(512), 0, stream>>>(
      x, table, Wih, Whh, bih, bhh, h0, c0, fcw, fcb,
      out, hN, cN, ring, HEXf, F_h, F_fc);
}